// Round 3
// baseline (171.924 us; speedup 1.0000x reference)
//
#include <hip/hip_runtime.h>
#include <stdint.h>

// ---------------------------------------------------------------------------
// MixingLayer: b=16, m=64, f=128, k=64, L2=16, LMAX=4. ALL I/O IS FP32.
// SEG = [0,1,1,1,2,2,2,2,2,3,3,3,3,3,3,3]
//
// Round-10: A-fragments (G) computed IN REGISTERS - sA eliminated.
//   * Each lane holds x[row_i, FB+2q..+1, c0..15] (32 dwords, loaded once)
//     and computes its own MFMA A-fragment per step from y (LDS stage).
//     Removes writeA + a-frag ds_reads + the per-step produce->barrier->
//     consume LDS round-trip that serialized every step (~3450 cy/step).
//   * 256-thread blocks, 2x2 wave grid over 64m x 128n; grid (64,16) =
//     1024 blocks = 4/CU, 30 KB LDS, 4 independent pipelines per CU.
//   * sB (pre-swizzled Wb2) + yS triple-buffered, counted-vmcnt barriers
//     (never 0 in steady state), DMAs issued 2 steps ahead.
//   * convert_all Wb2 pass rewritten source-coalesced (reads contiguous,
//     writes 64B-line-grouped scatter).
//
// ws layout (bytes):
//   Wb2 bf16 [16fb][128fy][128n][32] @ 0        (16,777,216)
//   xb  bf16 [1024 m][128 f][16] @ 16777216     ( 4,194,304)
//   yb  bf16 [1024 m][128 f][16] @ 20971520     ( 4,194,304)
//   Cpart f32 [64][1024][128]    @ 25165824     (33,554,432)
//   wfT f32 [2][64 k][4 l][128f] @ 58720256     (   262,144)
// ---------------------------------------------------------------------------

#define AS1 __attribute__((address_space(1)))
#define AS3 __attribute__((address_space(3)))

typedef __bf16 bf16x8 __attribute__((ext_vector_type(8)));
typedef float f32x4 __attribute__((ext_vector_type(4)));

__device__ __forceinline__ uint16_t f2b(float f) {
  uint32_t u = __float_as_uint(f);
  u += 0x7fffu + ((u >> 16) & 1u);   // RNE
  return (uint16_t)(u >> 16);
}

#if __has_builtin(__builtin_amdgcn_fdot2_f32_bf16)
typedef __bf16 bf16x2 __attribute__((ext_vector_type(2)));
__device__ __forceinline__ float dot2b(uint32_t a, uint32_t b, float c) {
  union { uint32_t u; bf16x2 v; } ua, ub;
  ua.u = a; ub.u = b;
  return __builtin_amdgcn_fdot2_f32_bf16(ua.v, ub.v, c, false);
}
#else
__device__ __forceinline__ float dot2b(uint32_t a, uint32_t b, float c) {
  float a0 = __uint_as_float(a << 16), a1 = __uint_as_float(a & 0xffff0000u);
  float b0 = __uint_as_float(b << 16), b1 = __uint_as_float(b & 0xffff0000u);
  return c + a0 * b0 + a1 * b1;
}
#endif

// ---------------------------------------------------------------------------
// K0: Wb2 (blocked, swizzle-baked, SOURCE-COALESCED) + xb/yb bf16 + wfT.
// grid: [0,4096) Wb2 ; [4096,6144) xb/yb ; [6144,6176) wfT.
// ---------------------------------------------------------------------------
__global__ __launch_bounds__(256) void convert_all(
    const float* __restrict__ wx0, const float* __restrict__ wy0,
    const float* __restrict__ x, const float* __restrict__ y,
    const float* __restrict__ wxf, const float* __restrict__ wyf,
    uint16_t* __restrict__ Wb2, uint16_t* __restrict__ xb,
    uint16_t* __restrict__ yb, float* __restrict__ wfT) {
  int bid = blockIdx.x, tid = threadIdx.x;
  if (bid < 4096) {  // Wb2: source-linear threads, 8 floats each
    size_t idx = ((size_t)bid * 256 + tid) * 8;   // over 2 x 4,194,304 floats
    int side = idx >= 4194304 ? 1 : 0;
    size_t rem = side ? idx - 4194304 : idx;      // flat [k][fy][fx][l]
    const float* src = (side ? wy0 : wx0) + rem;
    float4 v0 = *(const float4*)src;
    float4 v1 = *(const float4*)(src + 4);
    int fx0 = (int)((rem >> 2) & 127);            // even
    int fy  = (int)((rem >> 9) & 127);
    int k   = (int)(rem >> 16);
    int n = side * 64 + k;
    int fb = fx0 >> 3;
    int slot = (fx0 >> 1) & 3;
    int pos = slot ^ ((n >> 1) & 3);              // bake sB read swizzle
    uint32_t o0 = (uint32_t)f2b(v0.x) | ((uint32_t)f2b(v0.y) << 16);
    uint32_t o1 = (uint32_t)f2b(v0.z) | ((uint32_t)f2b(v0.w) << 16);
    uint32_t o2 = (uint32_t)f2b(v1.x) | ((uint32_t)f2b(v1.y) << 16);
    uint32_t o3 = (uint32_t)f2b(v1.z) | ((uint32_t)f2b(v1.w) << 16);
    size_t chunk = (((size_t)(fb * 128 + fy)) * 128 + n) * 4 + pos;
    *(uint4*)(Wb2 + chunk * 8) = make_uint4(o0, o1, o2, o3);
    return;
  }
  if (bid >= 6144) {  // wfT: 32 blocks x 256 thr x 8 elems = 65536
    int base = (bid - 6144) * 2048 + tid * 8;
#pragma unroll
    for (int ii = 0; ii < 8; ++ii) {
      int idx = base + ii;
      int side = idx >> 15, rem = idx & 32767;
      int k = rem >> 9, l = (rem >> 7) & 3, f = rem & 127;
      const float* src = side ? wyf : wxf;
      wfT[idx] = src[((size_t)l * 128 + f) * 64 + k];
    }
    return;
  }
  size_t i = ((size_t)(bid - 4096) * 256 + tid) * 8;
  const float* s; uint16_t* d;
  if (i < 2097152) { s = x + i;             d = xb + i; }
  else             { s = y + (i - 2097152); d = yb + (i - 2097152); }
  float4 v0 = *(const float4*)s;
  float4 v1 = *(const float4*)(s + 4);
  uint32_t o0 = (uint32_t)f2b(v0.x) | ((uint32_t)f2b(v0.y) << 16);
  uint32_t o1 = (uint32_t)f2b(v0.z) | ((uint32_t)f2b(v0.w) << 16);
  uint32_t o2 = (uint32_t)f2b(v1.x) | ((uint32_t)f2b(v1.y) << 16);
  uint32_t o3 = (uint32_t)f2b(v1.z) | ((uint32_t)f2b(v1.w) << 16);
  *(uint4*)d = make_uint4(o0, o1, o2, o3);
}

// ---------------------------------------------------------------------------
// K1: FUSED G-gen(in-reg) + split GEMM, 4 waves, counted-vmcnt pipeline.
// grid (64 groups, 16 M-tiles); group g: fb = g>>2, fyg = g&3 (32 fy).
// 32 steps, step t: fy = fyg*32 + t. Tile 64m x 128n per block.
// ---------------------------------------------------------------------------
__device__ __forceinline__ void gload_lds16(const void* g, void* l) {
  __builtin_amdgcn_global_load_lds((const AS1 uint32_t*)g, (AS3 uint32_t*)l, 16, 0, 0);
}

#define PIPE_BAR(N) \
  asm volatile("s_waitcnt vmcnt(" #N ") lgkmcnt(0)\n\ts_barrier" ::: "memory")

__global__ __launch_bounds__(256, 4) void fused_gemm(
    const uint16_t* __restrict__ xb, const uint16_t* __restrict__ yb,
    const uint16_t* __restrict__ Wb2, float* __restrict__ Cpart) {
  __shared__ __align__(16) uint16_t sB[3][128 * 32];  // swizzle baked in Wb2
  __shared__ __align__(16) uint16_t yS[3][1024];      // [chunk(2)][m(64)][8c]

  int tid = threadIdx.x;
  int w = tid >> 6, lane = tid & 63;
  int g_id = blockIdx.x;            // 0..63
  int fb = g_id >> 2, fyg = g_id & 3;
  int FB = fb * 8;
  int fy0 = fyg * 32;
  int m0 = blockIdx.y * 64;
  int r = lane & 15, q = lane >> 4;
  int wm = w >> 1, wn = w & 1;      // 2 x 2 wave grid over 64m x 128n

  // ---- one-time: x[m0 + wm*32 + i*16 + r, FB+2q .. +2, c0..15] -> 32 dwords
  uint32_t xreg[2][16];
#pragma unroll
  for (int i = 0; i < 2; ++i) {
    const uint16_t* xp0 =
        xb + (size_t)(m0 + wm * 32 + i * 16 + r) * 2048 + (FB + 2 * q) * 16;
#pragma unroll
    for (int j2 = 0; j2 < 4; ++j2) {
      uint4 v = *(const uint4*)(xp0 + j2 * 8);
      xreg[i][j2 * 4 + 0] = v.x; xreg[i][j2 * 4 + 1] = v.y;
      xreg[i][j2 * 4 + 2] = v.z; xreg[i][j2 * 4 + 3] = v.w;
    }
  }

  f32x4 zero = {0.f, 0.f, 0.f, 0.f};
  f32x4 acc[2][4];
#pragma unroll
  for (int i = 0; i < 2; ++i)
#pragma unroll
    for (int j = 0; j < 4; ++j) acc[i][j] = zero;

  int fbfy = fb * 128 + fy0;
  // B DMA: every wave loads blocks {2w, 2w+1} (16 n-rows, 1 KB each).
  auto issueB = [&](uint16_t* dstB, int t) {
    size_t base = (size_t)(fbfy + t) * 4096;  // halves
    gload_lds16(Wb2 + base + (size_t)(w * 2) * 512 + lane * 8,
                dstB + (w * 2) * 512);
    gload_lds16(Wb2 + base + (size_t)(w * 2 + 1) * 512 + lane * 8,
                dstB + (w * 2 + 1) * 512);
  };
  // Y DMA: waves 0,1 each load one c-half of y[m0..m0+64, fy] (1 KB).
  const uint16_t* ysrc = yb + (size_t)(m0 + lane) * 2048 + w * 8;
  auto issueY = [&](uint16_t* dstY, int t) {
    if (w < 2) gload_lds16(ysrc + (size_t)(fy0 + t) * 16, dstY + w * 512);
  };

  // ---- prologue: stage sets 0 and 1; set 0 landed, set 1 in flight.
  issueB(sB[0], 0); issueY(yS[0], 0);
  issueB(sB[1], 1); issueY(yS[1], 1);
  if (w < 2) PIPE_BAR(3); else PIPE_BAR(2);

  uint16_t *pB0 = sB[0], *pB1 = sB[1], *pB2 = sB[2];
  uint16_t *pY0 = yS[0], *pY1 = yS[1], *pY2 = yS[2];

  for (int t = 0; t < 32; ++t) {
    if (t <= 29) { issueB(pB2, t + 2); issueY(pY2, t + 2); }

    // B fragments (4 n-tiles)
    bf16x8 b[4];
#pragma unroll
    for (int j = 0; j < 4; ++j) {
      int row = wn * 64 + j * 16 + r;
      int pos = q ^ ((row >> 1) & 3);
      b[j] = *(const bf16x8*)&pB0[row * 32 + pos * 8];
    }
    // y rows for this lane's 2 m-tiles (16 distinct addrs/wave, broadcast)
    uint32_t yw[2][8];
#pragma unroll
    for (int i = 0; i < 2; ++i) {
      int row = wm * 32 + i * 16 + r;
      uint4 a0 = *(const uint4*)&pY0[row * 8];        // c0..7
      uint4 a1 = *(const uint4*)&pY0[512 + row * 8];  // c8..15
      yw[i][0] = a0.x; yw[i][1] = a0.y; yw[i][2] = a0.z; yw[i][3] = a0.w;
      yw[i][4] = a1.x; yw[i][5] = a1.y; yw[i][6] = a1.z; yw[i][7] = a1.w;
    }

#pragma unroll
    for (int i = 0; i < 2; ++i) {
      uint32_t yl0 = yw[i][0] & 0xffffu, yh0 = yw[i][0] & 0xffff0000u;
      uint32_t yl4 = yw[i][4] & 0xffffu, yh4 = yw[i][4] & 0xffff0000u;
      union { uint32_t u[4]; bf16x8 v; } af;
#pragma unroll
      for (int fxp = 0; fxp < 2; ++fxp) {
        const uint32_t* xp = &xreg[i][fxp * 8];
        float g0 = dot2b(xp[0], yl0, 0.f);
        float g1 = dot2b(xp[1], yw[i][1], dot2b(xp[0], yh0, 0.f));
        float g2 = dot2b(xp[4], yl4,
                    dot2b(xp[3], yw[i][3], dot2b(xp[2], yw[i][2], 0.f)));
        float g3 = dot2b(xp[7], yw[i][7], dot2b(xp[6], yw[i][6],
                    dot2b(xp[5], yw[i][5], dot2b(xp[4], yh4, 0.f))));
        af.u[fxp * 2 + 0] = (__float_as_uint(g0) >> 16) |
                            (__float_as_uint(g1) & 0xffff0000u);
        af.u[fxp * 2 + 1] = (__float_as_uint(g2) >> 16) |
                            (__float_as_uint(g3) & 0xffff0000u);
      }
      __builtin_amdgcn_s_setprio(1);
#pragma unroll
      for (int j = 0; j < 4; ++j)
        acc[i][j] = __builtin_amdgcn_mfma_f32_16x16x32_bf16(af.v, b[j],
                                                            acc[i][j], 0, 0, 0);
      __builtin_amdgcn_s_setprio(0);
    }

    if (t <= 29)      { if (w < 2) PIPE_BAR(3); else PIPE_BAR(2); }
    else if (t == 30) PIPE_BAR(0);
    // t == 31: no barrier; straight to epilogue

    uint16_t* tp;
    tp = pB0; pB0 = pB1; pB1 = pB2; pB2 = tp;
    tp = pY0; pY0 = pY1; pY1 = pY2; pY2 = tp;
  }

  // C/D layout: col(n)=lane&15, row(m)=(lane>>4)*4+reg
  float* cbase = Cpart + (size_t)g_id * 131072;  // 1024*128 per partial
#pragma unroll
  for (int i = 0; i < 2; ++i)
#pragma unroll
    for (int j = 0; j < 4; ++j)
#pragma unroll
      for (int reg = 0; reg < 4; ++reg) {
        int mm = m0 + wm * 32 + i * 16 + q * 4 + reg;
        int nn = wn * 64 + j * 16 + r;
        cbase[(size_t)mm * 128 + nn] = acc[i][j][reg];
      }
}

// ---------------------------------------------------------------------------
// K2: ONE BLOCK PER bm: inline 64-partial reduce, MLP, gates via wfT, output.
// ---------------------------------------------------------------------------
__global__ __launch_bounds__(256) void finish_kernel(
    const float* __restrict__ x, const float* __restrict__ y,
    const float* __restrict__ wx_mlp, const float* __restrict__ bx_mlp,
    const float* __restrict__ wy_mlp, const float* __restrict__ by_mlp,
    const float* __restrict__ wfT,
    const float* __restrict__ Cpart, float* __restrict__ out) {
  const int seg[16] = {0,1,1,1,2,2,2,2,2,3,3,3,3,3,3,3};
  __shared__ float sred[256];
  __shared__ float sm[128];
  __shared__ float sg[2][128][4];
  int t = threadIdx.x;
  int bm = blockIdx.x;
  int mi = bm & 63;

  {  // inline split-K reduction: sm[n] = sum_{sp<64} Cpart[sp][bm][n]
    int col = t & 127, hh = t >> 7;
    const float* cp = Cpart + (size_t)(hh * 32) * 131072 + (size_t)bm * 128 + col;
    float s = 0.f;
#pragma unroll 8
    for (int sp = 0; sp < 32; ++sp)
      s += cp[(size_t)sp * 131072];
    sred[t] = s;
  }
  __syncthreads();
  if (t < 128) sm[t] = sred[t] + sred[t + 128];  // [0:64)=mx, [64:128)=my
  __syncthreads();

  for (int st = 0; st < 2; ++st) {
    float v = 0.f;
    if (t < 128) {
      int side = t >> 6, j = t & 63;
      const float* wmlp = side ? wy_mlp : wx_mlp;
      const float* bmlp = side ? by_mlp : bx_mlp;
      const float* mv = sm + side * 64;
#pragma unroll 8
      for (int k = 0; k < 64; ++k)
        v += mv[k] * wmlp[(st * 64 + k) * 64 + j];
      v += bmlp[(st * 64 + mi) * 64 + j];
      v = v / (1.f + __expf(-v));
    }
    __syncthreads();
    if (t < 128) sm[t] = v;
    __syncthreads();
  }

  {  // gates: side wave-uniform, coalesced wfT reads
    int side = t >> 7, f = t & 127;
    const float* base = wfT + side * 32768;  // [k][l][f]
    const float* mv = sm + side * 64;
    float gg[4] = {0.f, 0.f, 0.f, 0.f};
#pragma unroll 8
    for (int k = 0; k < 64; ++k) {
      float m2 = mv[k];
#pragma unroll
      for (int l = 0; l < 4; ++l)
        gg[l] += m2 * base[(k * 4 + l) * 128 + f];
    }
#pragma unroll
    for (int l = 0; l < 4; ++l)
      sg[side][f][l] = gg[l] / (1.f + __expf(-gg[l]));
  }
  __syncthreads();

  {  // output: thread -> (f, half), 8 floats; fully coalesced
    int f = t >> 1, half = t & 1;
    size_t base = ((size_t)bm * 128 + f) * 16 + half * 8;
    float4 xa = *(const float4*)(x + base), xb4 = *(const float4*)(x + base + 4);
    float4 ya = *(const float4*)(y + base), yb4 = *(const float4*)(y + base + 4);
    float xv[8] = {xa.x, xa.y, xa.z, xa.w, xb4.x, xb4.y, xb4.z, xb4.w};
    float yv[8] = {ya.x, ya.y, ya.z, ya.w, yb4.x, yb4.y, yb4.z, yb4.w};
    float o[8];
#pragma unroll
    for (int ii = 0; ii < 8; ++ii) {
      int c = half * 8 + ii;
      o[ii] = sg[0][f][seg[c]] * xv[ii] + sg[1][f][seg[c]] * yv[ii];
    }
    *(float4*)(out + base)     = make_float4(o[0], o[1], o[2], o[3]);
    *(float4*)(out + base + 4) = make_float4(o[4], o[5], o[6], o[7]);
  }
}

// ---------------------------------------------------------------------------
extern "C" void kernel_launch(void* const* d_in, const int* in_sizes, int n_in,
                              void* d_out, int out_size, void* d_ws, size_t ws_size,
                              hipStream_t stream) {
  const float* x      = (const float*)d_in[0];
  const float* y      = (const float*)d_in[1];
  const float* wx0    = (const float*)d_in[2];
  const float* wy0    = (const float*)d_in[3];
  const float* wx_mlp = (const float*)d_in[4];
  const float* bx_mlp = (const float*)d_in[5];
  const float* wy_mlp = (const float*)d_in[6];
  const float* by_mlp = (const float*)d_in[7];
  const float* wxf    = (const float*)d_in[8];
  const float* wyf    = (const float*)d_in[9];
  float* out = (float*)d_out;

  uint16_t* Wb2   = (uint16_t*)d_ws;                               // 16,777,216 B
  uint16_t* xb    = (uint16_t*)((char*)d_ws + (size_t)16777216);   //  4,194,304 B
  uint16_t* yb    = (uint16_t*)((char*)d_ws + (size_t)20971520);   //  4,194,304 B
  float*    Cpart = (float*)((char*)d_ws + (size_t)25165824);      // 33,554,432 B
  float*    wfT   = (float*)((char*)d_ws + (size_t)58720256);      //    262,144 B

  convert_all<<<6176, 256, 0, stream>>>(wx0, wy0, x, y, wxf, wyf, Wb2, xb, yb, wfT);
  fused_gemm<<<dim3(64, 16), 256, 0, stream>>>(xb, yb, Wb2, Cpart);
  finish_kernel<<<1024, 256, 0, stream>>>(x, y, wx_mlp, bx_mlp, wy_mlp, by_mlp,
                                          wfT, Cpart, out);
}